// Round 10
// baseline (127.979 us; speedup 1.0000x reference)
//
#include <hip/hip_runtime.h>
#include <hip/hip_bf16.h>

// Deformable conv via FUSED implicit GEMM on MFMA.
// B=8, C=256, H=W=64, O=256, K=3.
// R10: producer/consumer wave specialization in dcn_fused.
//   waves 0-3: sample A-tile (gather+lerp) + stage B via global_load_lds,
//              2-deep gather pipeline, counted vmcnt(8) barriers.
//   waves 4-7: ds_read + 32 MFMA per step (64x128 tile each), no vmem.
//   One s_barrier per K-step; 2-buffer LDS (parity-disjoint).

#define HW 64
#define CCH 256
#define OCH 256
#define BB 8
#define KDIM 2304  // 9 * 256, order kk*256 + c

typedef __attribute__((ext_vector_type(8))) short bf16x8;
typedef __attribute__((ext_vector_type(8))) unsigned short u16x8;
typedef __attribute__((ext_vector_type(4))) float f32x4;
typedef __attribute__((ext_vector_type(2))) float f32x2;
typedef __attribute__((ext_vector_type(4))) unsigned short u16x4;
typedef __attribute__((ext_vector_type(4))) unsigned int u32x4;

static __device__ inline unsigned short f2bf(float f) {
  unsigned u = __builtin_bit_cast(unsigned, f);
  u += 0x7FFFu + ((u >> 16) & 1u);  // RNE
  return (unsigned short)(u >> 16);
}
static __device__ inline float bf2f(unsigned short s) {
  return __builtin_bit_cast(float, (unsigned)s << 16);
}
static __device__ inline unsigned cvt_pk_bf16(float lo, float hi) {
  unsigned r;
  asm("v_cvt_pk_bf16_f32 %0, %1, %2" : "=v"(r) : "v"(lo), "v"(hi));
  return r;
}

#define GLL16(gsrc, ldst)                                                      \
  __builtin_amdgcn_global_load_lds(                                           \
      (const __attribute__((address_space(1))) void*)(gsrc),                  \
      (__attribute__((address_space(3))) void*)(ldst), 16, 0, 0)

static __device__ inline int xcd_swz256(int bid) {
  return (bid & 7) * 32 + (bid >> 3);
}

// ---------------- prep ----------------
__global__ __launch_bounds__(256) void prep(const float* __restrict__ w_dcn,
                                            const float* __restrict__ w_off,
                                            unsigned short* __restrict__ W2,
                                            unsigned short* __restrict__ Wop,
                                            unsigned short* __restrict__ zp) {
  int i = blockIdx.x * 256 + threadIdx.x;
  if (i < 9 * 256 * 256) {
    int o = i / KDIM;
    int r = i - o * KDIM;
    int kk = r >> 8, c = r & 255;
    W2[i] = f2bf(w_dcn[((o << 8) + c) * 9 + kk]);
  }
  if (i < 32 * KDIM) {
    int n = i / KDIM;
    int r = i - n * KDIM;
    int kk = r >> 8, c = r & 255;
    Wop[i] = (n < 18) ? f2bf(w_off[((n << 8) + c) * 9 + kk]) : (unsigned short)0;
  }
  if (i < 512) zp[i] = 0;
}

// ---------------- xpose: NCHW f32 -> NHWC bf16 ----------------
__global__ __launch_bounds__(256) void xpose(const float* __restrict__ x,
                                             unsigned short* __restrict__ xTbf) {
  __shared__ float t[64][65];
  const int tid = threadIdx.x;
  const int bid = blockIdx.x;
  const int ct = bid & 3;
  const int pt = (bid >> 2) & 63;
  const int b = bid >> 8;
#pragma unroll
  for (int i = 0; i < 16; ++i) {
    int cl = i * 4 + (tid >> 6);
    int p = tid & 63;
    t[cl][p] = x[(((b << 8) + ct * 64 + cl) << 12) + pt * 64 + p];
  }
  __syncthreads();
#pragma unroll
  for (int i = 0; i < 4; ++i) {
    int pl = i * 16 + (tid >> 4);
    int c4 = (tid & 15) * 4;
    u16x4 v;
    v[0] = f2bf(t[c4][pl]);
    v[1] = f2bf(t[c4 + 1][pl]);
    v[2] = f2bf(t[c4 + 2][pl]);
    v[3] = f2bf(t[c4 + 3][pl]);
    *(u16x4*)(xTbf + (((size_t)((b << 12) + pt * 64 + pl)) << 8) + ct * 64 + c4) = v;
  }
}

// ---------------- offset_gemm (unchanged, validated) ----------------
__global__ __launch_bounds__(256) void offset_gemm(
    const unsigned short* __restrict__ xTbf, const unsigned short* __restrict__ Wop,
    const unsigned short* __restrict__ zp, const float* __restrict__ b_off,
    float* __restrict__ off_buf) {
  __shared__ short ldsA[2][128 * 32];
  __shared__ short ldsB[2][32 * 32];
  const int tid = threadIdx.x;
  const int lane = tid & 63;
  const int wid = __builtin_amdgcn_readfirstlane(tid >> 6);
  const int m0 = xcd_swz256(blockIdx.x) * 128;
  const int b = m0 >> 12;
  const unsigned short* xb = xTbf + ((size_t)b << 20);

  int hA[2], wA[2], scA[2];
#pragma unroll
  for (int g = 0; g < 2; ++g) {
    int r = wid * 32 + g * 16 + (lane >> 2);
    int pos = (m0 & 4095) + r;
    hA[g] = pos >> 6;
    wA[g] = pos & 63;
    scA[g] = ((lane & 3) ^ ((r >> 1) & 3)) * 8;
  }
  const int rB = wid * 16 + (lane >> 2);
  const unsigned short* srcB =
      Wop + (size_t)rB * KDIM + ((lane & 3) ^ ((rB >> 1) & 3)) * 8;

  const int l15 = lane & 15, l4 = lane >> 4;
  int offA[2], offB[2];
#pragma unroll
  for (int f = 0; f < 2; ++f) {
    int rA = wid * 32 + f * 16 + l15;
    offA[f] = rA * 32 + ((l4 ^ ((rA >> 1) & 3)) << 3);
    int rb = f * 16 + l15;
    offB[f] = rb * 32 + ((l4 ^ ((rb >> 1) & 3)) << 3);
  }

  const f32x4 z = {0.f, 0.f, 0.f, 0.f};
  f32x4 acc[2][2];
#pragma unroll
  for (int i = 0; i < 2; ++i)
#pragma unroll
    for (int j = 0; j < 2; ++j) acc[i][j] = z;

  auto stage = [&](int buf, int t) {
    const int kk = t >> 3;
    const int c0 = (t & 7) * 32;
    const int dy = kk / 3 - 1, dx = kk - (kk / 3) * 3 - 1;
#pragma unroll
    for (int g = 0; g < 2; ++g) {
      const int y = hA[g] + dy, xx = wA[g] + dx;
      const bool valid = ((unsigned)y < 64u) && ((unsigned)xx < 64u);
      const unsigned short* src =
          valid ? xb + ((((y << 6) + xx) << 8) + c0 + scA[g]) : zp + scA[g];
      GLL16(src, &ldsA[buf][((wid * 2 + g) * 64 + lane) * 8]);
    }
    if (wid < 2) GLL16(srcB + t * 32, &ldsB[buf][(wid * 64 + lane) * 8]);
  };

  stage(0, 0);
  __syncthreads();

  for (int t = 0; t < 72; ++t) {
    const int buf = t & 1;
    if (t < 71) stage(buf ^ 1, t + 1);
    bf16x8 af[2], bfr[2];
#pragma unroll
    for (int f = 0; f < 2; ++f) af[f] = *(const bf16x8*)&ldsA[buf][offA[f]];
#pragma unroll
    for (int f = 0; f < 2; ++f) bfr[f] = *(const bf16x8*)&ldsB[buf][offB[f]];
#pragma unroll
    for (int i = 0; i < 2; ++i)
#pragma unroll
      for (int j = 0; j < 2; ++j)
        acc[i][j] = __builtin_amdgcn_mfma_f32_16x16x32_bf16(af[i], bfr[j],
                                                            acc[i][j], 0, 0, 0);
    __syncthreads();
  }

#pragma unroll
  for (int j = 0; j < 2; ++j) {
    const int col = j * 16 + l15;
    if (col < 18) {
      const float bias = b_off[col];
#pragma unroll
      for (int i = 0; i < 2; ++i)
#pragma unroll
        for (int r = 0; r < 4; ++r) {
          const int m = m0 + wid * 32 + i * 16 + l4 * 4 + r;
          off_buf[(size_t)m * 18 + col] = acc[i][j][r] + bias;
        }
    }
  }
}

// ---------------- dcn_fused (R10: producer/consumer waves) ----------------
// BM=128, BN=256, BK=32, 72 K-steps. 512 threads, grid=256 (1 block/CU).
// Producers (wid 0-3): thread (r=ptid>>1, g2=ptid&1) samples 16 ch of row r.
// Consumers (wid 4-7): wave tile 64x128 (wm=wc&1, wn=wc>>1), acc[4][8].
__global__ __launch_bounds__(512, 2) void dcn_fused(
    const unsigned short* __restrict__ xTbf, const float* __restrict__ off_buf,
    const unsigned short* __restrict__ W2, float* __restrict__ out) {
  __shared__ f32x2 slyx[128][9];   // (ly, lx)
  __shared__ u16x4 spos[128][9];   // corner pos (12b) | validity<<15
  __shared__ short ldsA[2][128 * 32];   // 16KB
  __shared__ short ldsB[2][256 * 32];   // 32KB

  const int tid = threadIdx.x;
  const int lane = tid & 63;
  const int wid = __builtin_amdgcn_readfirstlane(tid >> 6);
  const int m0 = xcd_swz256(blockIdx.x) * 128;
  const int b = m0 >> 12;
  const unsigned short* xb = xTbf + ((size_t)b << 20);

  // ---- phase 0: sampling params for 128 rows x 9 taps (all waves) ----
  for (int idx = tid; idx < 128 * 9; idx += 512) {
    const int r = idx / 9, k = idx - (idx / 9) * 9;
    const int ky = k / 3, kx = k - ky * 3;
    const int pos = (m0 & 4095) + r;
    const int h = pos >> 6, w = pos & 63;
    const float offy = off_buf[(size_t)(m0 + r) * 18 + 2 * k];
    const float offx = off_buf[(size_t)(m0 + r) * 18 + 2 * k + 1];
    const float sy = offy + (float)(h - 1 + ky);
    const float sx = offx + (float)(w - 1 + kx);
    const float y0f = floorf(sy), x0f = floorf(sx);
    const int y0 = (int)y0f, x0 = (int)x0f;
    const int y1 = y0 + 1, x1 = x0 + 1;
    const unsigned vy0 = ((unsigned)y0 < 64u), vy1 = ((unsigned)y1 < 64u);
    const unsigned vx0 = ((unsigned)x0 < 64u), vx1 = ((unsigned)x1 < 64u);
    const int y0c = min(max(y0, 0), HW - 1), y1c = min(max(y1, 0), HW - 1);
    const int x0c = min(max(x0, 0), HW - 1), x1c = min(max(x1, 0), HW - 1);
    f32x2 lyx;
    lyx[0] = sy - y0f;
    lyx[1] = sx - x0f;
    u16x4 pp;
    pp[0] = (unsigned short)(((y0c << 6) + x0c) | ((vy0 & vx0) << 15));
    pp[1] = (unsigned short)(((y0c << 6) + x1c) | ((vy0 & vx1) << 15));
    pp[2] = (unsigned short)(((y1c << 6) + x0c) | ((vy1 & vx0) << 15));
    pp[3] = (unsigned short)(((y1c << 6) + x1c) | ((vy1 & vx1) << 15));
    slyx[r][k] = lyx;
    spos[r][k] = pp;
  }
  __syncthreads();

  if (wid < 4) {
    // =================== PRODUCERS ===================
    const int ptid = tid;        // 0..255
    const int r = ptid >> 1;     // row 0..127
    const int g2 = ptid & 1;     // 16-ch half of the 32-ch K-tile
    const int g2h = g2 * 16;
    // A write slots (shorts): chunks {2g2, 2g2+1} ^ ((r>>1)&3). 2-way max.
    const int dstA0 = r * 32 + (((2 * g2) ^ ((r >> 1) & 3)) << 3);
    const int dstA1 = r * 32 + (((2 * g2 + 1) ^ ((r >> 1) & 3)) << 3);
    // B staging: 4 GLL16/thread; dst lane-linear, source pre-swizzled.
    const unsigned short* srcBp[4];
    int dstB[4];
#pragma unroll
    for (int g = 0; g < 4; ++g) {
      const int idx = g * 256 + ptid;
      const int row = idx >> 2, c = idx & 3;
      srcBp[g] = W2 + (size_t)row * KDIM + ((c ^ ((row >> 1) & 3)) << 3);
      dstB[g] = idx * 8;
    }

    f32x4 wv;
    int av[4];
    auto load_params = [&](int tap) {
      const f32x2 lyx = slyx[r][tap];
      const u16x4 pp = spos[r][tap];
      const float ly = lyx[0], lx = lyx[1];
#pragma unroll
      for (int e = 0; e < 4; ++e) av[e] = (int)(pp[e] & 0x0FFFu) << 8;
      wv[0] = (1.f - ly) * (1.f - lx) * (float)(pp[0] >> 15);
      wv[1] = (1.f - ly) * lx * (float)(pp[1] >> 15);
      wv[2] = ly * (1.f - lx) * (float)(pp[2] >> 15);
      wv[3] = ly * lx * (float)(pp[3] >> 15);
    };

    auto lerp_store = [&](int buf, const u16x8 (&gc)[4][2], const f32x4& gw) {
#pragma unroll
      for (int h = 0; h < 2; ++h) {
        u32x4 wds;
#pragma unroll
        for (int e = 0; e < 4; ++e) {
          const float f0 =
              gw[0] * bf2f(gc[0][h][2 * e]) + gw[1] * bf2f(gc[1][h][2 * e]) +
              gw[2] * bf2f(gc[2][h][2 * e]) + gw[3] * bf2f(gc[3][h][2 * e]);
          const float f1 = gw[0] * bf2f(gc[0][h][2 * e + 1]) +
                           gw[1] * bf2f(gc[1][h][2 * e + 1]) +
                           gw[2] * bf2f(gc[2][h][2 * e + 1]) +
                           gw[3] * bf2f(gc[3][h][2 * e + 1]);
          wds[e] = cvt_pk_bf16(f0, f1);
        }
        *(u32x4*)&ldsA[buf][h == 0 ? dstA0 : dstA1] = wds;
      }
    };

    u16x8 gA[4][2], gB[4][2];  // 2-deep gather pipeline sets
    f32x4 wA, wB;

    // ---- prologue: tile 0 sampled inline; B(0) staged; gathers(1) issued ----
    load_params(0);
    {
#pragma unroll
      for (int c = 0; c < 4; ++c) {
        gA[c][0] = *(const u16x8*)(xb + av[c] + g2h);
        gA[c][1] = *(const u16x8*)(xb + av[c] + g2h + 8);
      }
      wA = wv;
    }
#pragma unroll
    for (int g = 0; g < 4; ++g) GLL16(srcBp[g], &ldsB[0][dstB[g]]);
    __builtin_amdgcn_sched_barrier(0);
    lerp_store(0, gA, wA);  // compiler waits gathers(0): vmcnt(4)
    {                        // gathers(1): tap 0, ch base 32
#pragma unroll
      for (int c = 0; c < 4; ++c) {
        gA[c][0] = *(const u16x8*)(xb + av[c] + 32 + g2h);
        gA[c][1] = *(const u16x8*)(xb + av[c] + 32 + g2h + 8);
      }
      wA = wv;
    }
    asm volatile("s_waitcnt vmcnt(8) lgkmcnt(0)" ::: "memory");  // drain GLL(0)
    __builtin_amdgcn_s_barrier();

// producer step T (0..69): stage B(T+1), gather tile T+2 -> OUT, lerp tile
// T+1 from IN, barrier with vmcnt(8) (drains GLL(T+1), keeps 8 gathers).
#define PSTEP(T, IN, INW, OUT, OUTW)                                           \
  {                                                                            \
    const int tn = (T) + 1;                                                    \
    _Pragma("unroll") for (int g = 0; g < 4; ++g)                              \
        GLL16(srcBp[g] + tn * 32, &ldsB[tn & 1][dstB[g]]);                     \
    __builtin_amdgcn_sched_barrier(0);                                         \
    {                                                                          \
      const int tg = (T) + 2;                                                  \
      if ((tg & 7) == 0) load_params(tg >> 3);                                 \
      const int cb = ((tg & 7) << 5) + g2h;                                    \
      _Pragma("unroll") for (int c = 0; c < 4; ++c) {                          \
        OUT[c][0] = *(const u16x8*)(xb + av[c] + cb);                          \
        OUT[c][1] = *(const u16x8*)(xb + av[c] + cb + 8);                      \
      }                                                                        \
      OUTW = wv;                                                               \
    }                                                                          \
    lerp_store(tn & 1, IN, INW);                                               \
    asm volatile("s_waitcnt vmcnt(8) lgkmcnt(0)" ::: "memory");                \
    __builtin_amdgcn_s_barrier();                                              \
  }

    for (int it = 0; it < 35; ++it) {
      const int t0 = it * 2;
      PSTEP(t0, gA, wA, gB, wB)
      PSTEP(t0 + 1, gB, wB, gA, wA)
    }
#undef PSTEP
    // ---- t=70: stage B(71), lerp tile 71 (in gA), full drain ----
    {
#pragma unroll
      for (int g = 0; g < 4; ++g) GLL16(srcBp[g] + 71 * 32, &ldsB[1][dstB[g]]);
      __builtin_amdgcn_sched_barrier(0);
      lerp_store(1, gA, wA);
      asm volatile("s_waitcnt vmcnt(0) lgkmcnt(0)" ::: "memory");
      __builtin_amdgcn_s_barrier();
    }
    // t=71: consumers compute; producers done (no barrier).
  } else {
    // =================== CONSUMERS ===================
    const int wc = wid - 4;
    const int wm = wc & 1, wn = wc >> 1;
    const int l15 = lane & 15, l4 = lane >> 4;
    int offA[4], offB[8];
#pragma unroll
    for (int f = 0; f < 4; ++f) {
      const int rA = wm * 64 + f * 16 + l15;
      offA[f] = rA * 32 + ((l4 ^ ((rA >> 1) & 3)) << 3);
    }
#pragma unroll
    for (int j = 0; j < 8; ++j) {
      const int rB = wn * 128 + j * 16 + l15;
      offB[j] = rB * 32 + ((l4 ^ ((rB >> 1) & 3)) << 3);
    }

    const f32x4 z = {0.f, 0.f, 0.f, 0.f};
    f32x4 acc[4][8];
#pragma unroll
    for (int i = 0; i < 4; ++i)
#pragma unroll
      for (int j = 0; j < 8; ++j) acc[i][j] = z;

    __builtin_amdgcn_s_barrier();  // matches producer prologue barrier

    for (int t = 0; t < 72; ++t) {
      const int buf = t & 1;
      bf16x8 af[4], bfr[8];
#pragma unroll
      for (int f = 0; f < 4; ++f) af[f] = *(const bf16x8*)&ldsA[buf][offA[f]];
#pragma unroll
      for (int j = 0; j < 8; ++j) bfr[j] = *(const bf16x8*)&ldsB[buf][offB[j]];
      __builtin_amdgcn_s_setprio(1);
#pragma unroll
      for (int i = 0; i < 4; ++i)
#pragma unroll
        for (int j = 0; j < 8; ++j)
          acc[i][j] = __builtin_amdgcn_mfma_f32_16x16x32_bf16(af[i], bfr[j],
                                                              acc[i][j], 0, 0, 0);
      __builtin_amdgcn_s_setprio(0);
      if (t < 71) {
        asm volatile("s_waitcnt lgkmcnt(0)" ::: "memory");
        __builtin_amdgcn_s_barrier();
      }
    }

    // ---- epilogue (consumers own all of C) ----
#pragma unroll
    for (int i = 0; i < 4; ++i) {
      const int m = m0 + wm * 64 + i * 16 + l4 * 4;
      const int bb = m >> 12;
      const int pos = m & 4095;
#pragma unroll
      for (int j = 0; j < 8; ++j) {
        const int o = wn * 128 + j * 16 + l15;
        *(f32x4*)(out + (((size_t)bb * OCH + o) << 12) + pos) = acc[i][j];
      }
    }
  }
}

extern "C" void kernel_launch(void* const* d_in, const int* in_sizes, int n_in,
                              void* d_out, int out_size, void* d_ws,
                              size_t ws_size, hipStream_t stream) {
  const float* x = (const float*)d_in[0];
  const float* w_off = (const float*)d_in[1];
  const float* b_off = (const float*)d_in[2];
  const float* w_dcn = (const float*)d_in[3];
  float* out = (float*)d_out;

  char* ws = (char*)d_ws;
  float* off_buf = (float*)(ws);                            //  2,359,296 B
  unsigned short* Wop = (unsigned short*)(ws + 2359296);    //    147,456 B
  unsigned short* zp = (unsigned short*)(ws + 2506752);     //      1,024 B
  unsigned short* W2 = (unsigned short*)(ws + 2507776);     //  1,179,648 B
  unsigned short* xTbf = (unsigned short*)(ws + 3687424);   // 16,777,216 B
  // total 20,464,640 B

  prep<<<2304, 256, 0, stream>>>(w_dcn, w_off, W2, Wop, zp);
  xpose<<<2048, 256, 0, stream>>>(x, xTbf);
  offset_gemm<<<256, 256, 0, stream>>>(xTbf, Wop, zp, b_off, off_buf);
  dcn_fused<<<256, 512, 0, stream>>>(xTbf, off_buf, W2, out);
}